// Round 1
// baseline (101.423 us; speedup 1.0000x reference)
//
#include <hip/hip_runtime.h>
#include <math.h>

#define TLEN 1024   // seq length (FFT size)
#define NLAYER 6
#define NTHREADS 512  // TLEN/2 butterflies per stage

__global__ __launch_bounds__(NTHREADS)
void phasor_kernel(const float* __restrict__ X,
                   const float* __restrict__ W,
                   float* __restrict__ out)
{
    __shared__ float2 bufA[TLEN];
    __shared__ float2 bufB[TLEN];
    __shared__ float2 twid[TLEN];   // 1023 used

    const int tid = threadIdx.x;
    const int row = blockIdx.x;

    // ---- twiddle table: entry e (0..1022): ep=e+1, s=floor(log2 ep),
    // Ns=2^s, j=ep-Ns  ->  twid[e] = exp(-i*pi*j/Ns)
    for (int e = tid; e < TLEN - 1; e += NTHREADS) {
        int ep = e + 1;
        int s  = 31 - __clz(ep);
        int Ns = 1 << s;
        int j  = ep - Ns;
        float ang = -3.14159265358979323846f * (float)j / (float)Ns;
        float sv, cv;
        sincosf(ang, &sv, &cv);
        twid[e] = make_float2(cv, sv);
    }

    // ---- encode: z = exp(i*arcsin(clip(x))) = (sqrt(1-x^2), x)
    const float* xrow = X + (size_t)row * TLEN;
    for (int t = tid; t < TLEN; t += NTHREADS) {
        float x = xrow[t];
        x = fminf(fmaxf(x, -0.999f), 0.999f);
        bufA[t] = make_float2(sqrtf(1.0f - x * x), x);
    }
    __syncthreads();

    // combined per-layer linear scale: (1/sqrt(2)) * (1/sqrt(1024))
    const float scale = 0.02209708691207961f;

    for (int l = 0; l < NLAYER; ++l) {
        // ---- variational shift + balanced mix (thread owns pair 2*tid, 2*tid+1)
        {
            int t0 = 2 * tid, t1 = t0 + 1;
            float2 za = bufA[t0], zb = bufA[t1];
            float w0 = W[l * TLEN + t0], w1 = W[l * TLEN + t1];
            float s0, c0, s1, c1;
            sincosf(w0, &s0, &c0);
            sincosf(w1, &s1, &c1);
            float2 pa = make_float2(za.x * c0 - za.y * s0, za.x * s0 + za.y * c0);
            float2 pb = make_float2(zb.x * c1 - zb.y * s1, zb.x * s1 + zb.y * c1);
            bufA[t0] = make_float2((pa.x + pb.x) * scale, (pa.y + pb.y) * scale);
            bufA[t1] = make_float2((pa.x - pb.x) * scale, (pa.y - pb.y) * scale);
        }
        __syncthreads();

        // ---- unitary DFT via Stockham radix-2 autosort (10 stages, A<->B)
        float2* src = bufA;
        float2* dst = bufB;
        #pragma unroll
        for (int s = 0; s < 10; ++s) {
            const int Ns = 1 << s;
            const int j  = tid;
            const int jm = j & (Ns - 1);
            float2 w = twid[Ns - 1 + jm];
            float2 a = src[j];
            float2 b = src[j + NTHREADS];
            float2 tb = make_float2(b.x * w.x - b.y * w.y,
                                    b.x * w.y + b.y * w.x);
            int idxD = ((j >> s) << (s + 1)) + jm;
            dst[idxD]      = make_float2(a.x + tb.x, a.y + tb.y);
            dst[idxD + Ns] = make_float2(a.x - tb.x, a.y - tb.y);
            __syncthreads();
            float2* t = src; src = dst; dst = t;
        }
        // 10 swaps (even): result is back in bufA
    }

    if (tid == 0) {
        float2 z0 = bufA[0];
        float mag = sqrtf(z0.x * z0.x + z0.y * z0.y);
        out[row] = (z0.y / mag + 1.0f) * 0.5f;
    }
}

extern "C" void kernel_launch(void* const* d_in, const int* in_sizes, int n_in,
                              void* d_out, int out_size, void* d_ws, size_t ws_size,
                              hipStream_t stream) {
    const float* X = (const float*)d_in[0];   // [4096, 1024]
    const float* W = (const float*)d_in[1];   // [6*1024]
    float* out = (float*)d_out;               // [4096]
    (void)in_sizes; (void)n_in; (void)d_ws; (void)ws_size; (void)out_size;

    phasor_kernel<<<4096, NTHREADS, 0, stream>>>(X, W, out);
}

// Round 2
// 100.583 us; speedup vs baseline: 1.0084x; 1.0084x over previous
//
#include <hip/hip_runtime.h>
#include <math.h>

#define TLEN 1024
#define NLAYER 6

__device__ __forceinline__ float2 cadd(float2 a, float2 b){ return make_float2(a.x+b.x, a.y+b.y); }
__device__ __forceinline__ float2 csub(float2 a, float2 b){ return make_float2(a.x-b.x, a.y-b.y); }
__device__ __forceinline__ float2 cmul(float2 a, float2 b){
    return make_float2(fmaf(a.x, b.x, -(a.y*b.y)), fmaf(a.x, b.y, a.y*b.x));
}
__device__ __forceinline__ float2 cmulnegi(float2 a){ return make_float2(a.y, -a.x); } // a * (-i)

__device__ __forceinline__ float2 shfl_xor2(float2 v, int m){
    return make_float2(__shfl_xor(v.x, m, 64), __shfl_xor(v.y, m, 64));
}

// DFT-4 (radix-2x2): y_k = sum_a x_a * W4^{a k}
__device__ __forceinline__ void dft4(float2 x0, float2 x1, float2 x2, float2 x3,
                                     float2& y0, float2& y1, float2& y2, float2& y3){
    float2 t0 = cadd(x0, x2);
    float2 t1 = csub(x0, x2);
    float2 t2 = cadd(x1, x3);
    float2 t3 = csub(x1, x3);
    float2 n3 = cmulnegi(t3);     // -i * t3
    y0 = cadd(t0, t2);
    y2 = csub(t0, t2);
    y1 = cadd(t1, n3);
    y3 = csub(t1, n3);
}

// in-lane 16-point DFT, natural in -> natural out (registers)
__device__ __forceinline__ void fft16(float2 z[16]){
    const float C1 = 0.92387953251128675613f, S1 = 0.38268343236508977173f;
    const float H  = 0.70710678118654752440f;
    const float2 W1 = make_float2( C1, -S1);   // W16^1
    const float2 W2 = make_float2(  H,  -H);   // W16^2
    const float2 W3 = make_float2( S1, -C1);   // W16^3
    const float2 W6 = make_float2( -H,  -H);   // W16^6
    const float2 W9 = make_float2(-C1,  S1);   // W16^9

    float2 A0[4], A1[4], A2[4], A3[4]; // A[k1][b]
    #pragma unroll
    for (int b = 0; b < 4; ++b)
        dft4(z[b], z[4+b], z[8+b], z[12+b], A0[b], A1[b], A2[b], A3[b]);

    // twiddle: A[k1][b] *= W16^{b*k1}
    A1[1] = cmul(A1[1], W1);  A1[2] = cmul(A1[2], W2);  A1[3] = cmul(A1[3], W3);
    A2[1] = cmul(A2[1], W2);  A2[2] = cmulnegi(A2[2]);  A2[3] = cmul(A2[3], W6);
    A3[1] = cmul(A3[1], W3);  A3[2] = cmul(A3[2], W6);  A3[3] = cmul(A3[3], W9);

    // out[k1 + 4*k2] = DFT4_b(A[k1][b])[k2]
    dft4(A0[0], A0[1], A0[2], A0[3], z[0], z[4], z[8],  z[12]);
    dft4(A1[0], A1[1], A1[2], A1[3], z[1], z[5], z[9],  z[13]);
    dft4(A2[0], A2[1], A2[2], A2[3], z[2], z[6], z[10], z[14]);
    dft4(A3[0], A3[1], A3[2], A3[3], z[3], z[7], z[11], z[15]);
}

// cross-lane DIF FFT-64 over lane index: natural input order, bit-reversed output order
__device__ __forceinline__ void xfft_dif(float2 z[16], const float2 wdif[6], int lane){
    #pragma unroll
    for (int s = 0; s < 6; ++s){
        const int h = 32 >> s;
        const bool up = (lane & h) != 0;
        const float2 w = wdif[s];
        #pragma unroll
        for (int r = 0; r < 16; ++r){
            float2 o  = shfl_xor2(z[r], h);
            float2 s1 = cadd(z[r], o);   // lower lane result
            float2 s2 = csub(o, z[r]);   // upper lane pre-twiddle (u - v)
            float2 sel = up ? s2 : s1;
            z[r] = cmul(sel, w);         // w == (1,0) on lower lanes
        }
    }
}

// cross-lane DIT FFT-64: bit-reversed input order -> natural output order
__device__ __forceinline__ void xfft_dit(float2 z[16], const float2 wdit[6], int lane){
    #pragma unroll
    for (int s = 0; s < 6; ++s){
        const int d = 1 << s;
        const bool up = (lane & d) != 0;
        const float2 w = wdit[s];        // upper lanes store -W (sign folded)
        #pragma unroll
        for (int r = 0; r < 16; ++r){
            float2 o    = shfl_xor2(z[r], d);
            float2 q    = up ? z[r] : o;
            float2 base = up ? o : z[r];
            z[r] = cadd(base, cmul(q, w));
        }
    }
}

__global__ __launch_bounds__(256)
void phasor_kernel(const float* __restrict__ X,
                   const float* __restrict__ W,
                   float* __restrict__ out)
{
    const int lane = threadIdx.x & 63;
    const int row  = blockIdx.x * 4 + (threadIdx.x >> 6);

    // bit-reverse-6 of lane
    const int c = ((lane & 1) << 5) | ((lane & 2) << 3) | ((lane & 4) << 1)
                | ((lane & 8) >> 1) | ((lane & 16) >> 3) | ((lane & 32) >> 5);

    // ---- per-lane twiddle tables (layer-independent) ----
    float2 wdif[6], wdit[6];
    #pragma unroll
    for (int s = 0; s < 6; ++s){
        const int h = 32 >> s;
        {
            int idx = lane & (h - 1);
            float sv, cv;
            sincosf(-3.14159265358979323846f * (float)idx / (float)h, &sv, &cv);
            wdif[s] = (lane & h) ? make_float2(cv, sv) : make_float2(1.0f, 0.0f);
        }
        {
            const int d = 1 << s;
            int idx = lane & (d - 1);
            float sv, cv;
            sincosf(-3.14159265358979323846f * (float)idx / (float)d, &sv, &cv);
            wdit[s] = (lane & d) ? make_float2(-cv, -sv) : make_float2(cv, sv);
        }
    }
    // mid twiddles: W_1024^{c*r}, r=0..15
    float2 wmid[16];
    {
        const float theta = -6.28318530717958647692f * (float)c / 1024.0f;
        #pragma unroll
        for (int r = 0; r < 16; ++r){
            float sv, cv;
            sincosf(theta * (float)r, &sv, &cv);
            wmid[r] = make_float2(cv, sv);
        }
    }

    // ---- load + encode: z = (sqrt(1-x^2), x), consecutive layout t = 16*lane + r ----
    float2 z[16];
    {
        const float4* px = (const float4*)(X + (size_t)row * TLEN + lane * 16);
        #pragma unroll
        for (int i = 0; i < 4; ++i){
            float4 v = px[i];
            float xs[4] = {v.x, v.y, v.z, v.w};
            #pragma unroll
            for (int j = 0; j < 4; ++j){
                float x = fminf(fmaxf(xs[j], -0.999f), 0.999f);
                z[4*i + j] = make_float2(sqrtf(fmaf(-x, x, 1.0f)), x);
            }
        }
    }

    const float SC = 0.02209708691207961f;  // (1/sqrt(2)) * (1/sqrt(1024))

    for (int lp = 0; lp < 3; ++lp){
        // ================= even layer (2*lp): consecutive layout =================
        {
            const float* wl = W + (2*lp) * TLEN + lane * 16;
            #pragma unroll
            for (int i = 0; i < 4; ++i){
                float4 wv = ((const float4*)wl)[i];
                float ws[4] = {wv.x, wv.y, wv.z, wv.w};
                #pragma unroll
                for (int j = 0; j < 4; ++j){
                    float sv, cv;
                    __sincosf(ws[j], &sv, &cv);
                    z[4*i + j] = cmul(z[4*i + j], make_float2(cv, sv));
                }
            }
            // mix: pairs are adjacent registers (t = 16*lane + r)
            #pragma unroll
            for (int m = 0; m < 8; ++m){
                float2 a = z[2*m], b = z[2*m + 1];
                z[2*m]     = make_float2((a.x + b.x) * SC, (a.y + b.y) * SC);
                z[2*m + 1] = make_float2((a.x - b.x) * SC, (a.y - b.y) * SC);
            }
            // DFT variant A: cross-lane DIF, mid twiddle, in-lane FFT-16
            xfft_dif(z, wdif, lane);
            #pragma unroll
            for (int r = 0; r < 16; ++r) z[r] = cmul(z[r], wmid[r]);
            fft16(z);
            // layout now strided-bitrev: lane owns column c, reg r holds t = 64r + c
        }
        // ================= odd layer (2*lp+1): strided-bitrev layout =================
        {
            const float* wl = W + (2*lp + 1) * TLEN + c;
            #pragma unroll
            for (int r = 0; r < 16; ++r){
                float wr = wl[r << 6];
                float sv, cv;
                __sincosf(wr, &sv, &cv);
                z[r] = cmul(z[r], make_float2(cv, sv));
            }
            // mix: partner is lane^32 (c^1), parity of t = bit0(c) = bit5(lane)
            const bool upm = (lane & 32) != 0;
            #pragma unroll
            for (int r = 0; r < 16; ++r){
                float2 o = shfl_xor2(z[r], 32);
                float2 res = upm ? csub(o, z[r]) : cadd(z[r], o);
                z[r] = make_float2(res.x * SC, res.y * SC);
            }
            // DFT variant B: in-lane FFT-16, mid twiddle, cross-lane DIT
            fft16(z);
            #pragma unroll
            for (int r = 0; r < 16; ++r) z[r] = cmul(z[r], wmid[r]);
            xfft_dit(z, wdit, lane);
            // layout now consecutive: lane l reg k1 holds k = 16*l + k1
        }
    }

    if (lane == 0){
        float2 z0 = z[0];
        out[row] = fmaf(z0.y * rsqrtf(fmaf(z0.x, z0.x, z0.y * z0.y)), 0.5f, 0.5f);
    }
}

extern "C" void kernel_launch(void* const* d_in, const int* in_sizes, int n_in,
                              void* d_out, int out_size, void* d_ws, size_t ws_size,
                              hipStream_t stream) {
    const float* X = (const float*)d_in[0];   // [4096, 1024]
    const float* W = (const float*)d_in[1];   // [6*1024]
    float* out = (float*)d_out;               // [4096]
    (void)in_sizes; (void)n_in; (void)d_ws; (void)ws_size; (void)out_size;

    phasor_kernel<<<4096 / 4, 256, 0, stream>>>(X, W, out);
}

// Round 3
// 67.929 us; speedup vs baseline: 1.4931x; 1.4807x over previous
//
#include <hip/hip_runtime.h>
#include <math.h>

#define TLEN 1024

__device__ __forceinline__ float2 cadd(float2 a, float2 b){ return make_float2(a.x+b.x, a.y+b.y); }
__device__ __forceinline__ float2 csub(float2 a, float2 b){ return make_float2(a.x-b.x, a.y-b.y); }
__device__ __forceinline__ float2 cmul(float2 a, float2 b){
    return make_float2(fmaf(a.x, b.x, -(a.y*b.y)), fmaf(a.x, b.y, a.y*b.x));
}
__device__ __forceinline__ float2 cmulnegi(float2 a){ return make_float2(a.y, -a.x); } // a * (-i)
__device__ __forceinline__ float2 shfl_xor2(float2 v, int m){
    return make_float2(__shfl_xor(v.x, m, 64), __shfl_xor(v.y, m, 64));
}
__device__ __forceinline__ int bitrev6(int l){
    return ((l & 1) << 5) | ((l & 2) << 3) | ((l & 4) << 1)
         | ((l & 8) >> 1) | ((l & 16) >> 3) | ((l & 32) >> 5);
}

// DFT-4 (radix-2x2)
__device__ __forceinline__ void dft4(float2 x0, float2 x1, float2 x2, float2 x3,
                                     float2& y0, float2& y1, float2& y2, float2& y3){
    float2 t0 = cadd(x0, x2);
    float2 t1 = csub(x0, x2);
    float2 t2 = cadd(x1, x3);
    float2 t3 = csub(x1, x3);
    float2 n3 = cmulnegi(t3);
    y0 = cadd(t0, t2);
    y2 = csub(t0, t2);
    y1 = cadd(t1, n3);
    y3 = csub(t1, n3);
}

// in-lane 16-point DFT, natural in -> natural out
__device__ __forceinline__ void fft16(float2 z[16]){
    const float C1 = 0.92387953251128675613f, S1 = 0.38268343236508977173f;
    const float H  = 0.70710678118654752440f;
    const float2 W1 = make_float2( C1, -S1);
    const float2 W2 = make_float2(  H,  -H);
    const float2 W3 = make_float2( S1, -C1);
    const float2 W6 = make_float2( -H,  -H);
    const float2 W9 = make_float2(-C1,  S1);

    float2 A0[4], A1[4], A2[4], A3[4];
    #pragma unroll
    for (int b = 0; b < 4; ++b)
        dft4(z[b], z[4+b], z[8+b], z[12+b], A0[b], A1[b], A2[b], A3[b]);

    A1[1] = cmul(A1[1], W1);  A1[2] = cmul(A1[2], W2);  A1[3] = cmul(A1[3], W3);
    A2[1] = cmul(A2[1], W2);  A2[2] = cmulnegi(A2[2]);  A2[3] = cmul(A2[3], W6);
    A3[1] = cmul(A3[1], W3);  A3[2] = cmul(A3[2], W6);  A3[3] = cmul(A3[3], W9);

    dft4(A0[0], A0[1], A0[2], A0[3], z[0], z[4], z[8],  z[12]);
    dft4(A1[0], A1[1], A1[2], A1[3], z[1], z[5], z[9],  z[13]);
    dft4(A2[0], A2[1], A2[2], A2[3], z[2], z[6], z[10], z[14]);
    dft4(A3[0], A3[1], A3[2], A3[3], z[3], z[7], z[11], z[15]);
}

// cross-lane DIF FFT-64: natural in -> bit-reversed out.
// butterfly: pre = o + sg*z  (sg=+1 lower / -1 upper), then *W on upper lanes.
__device__ __forceinline__ void xfft_dif(float2 z[16], const float2 Wt[5], int lane){
    #pragma unroll
    for (int s = 0; s < 6; ++s){
        const int h = 32 >> s;
        const bool up = (lane & h) != 0;
        const float sg = up ? -1.0f : 1.0f;
        float2 w;
        if (h > 1) w = up ? Wt[4 - s] : make_float2(1.0f, 0.0f);
        #pragma unroll
        for (int r = 0; r < 16; ++r){
            float2 o = shfl_xor2(z[r], h);
            float2 pre = make_float2(fmaf(sg, z[r].x, o.x), fmaf(sg, z[r].y, o.y));
            z[r] = (h > 1) ? cmul(pre, w) : pre;
        }
    }
}

// cross-lane DIT FFT-64: bit-reversed in -> natural out.
// pre-twiddle own value on upper lanes, exchange, then o + sg*zz.
__device__ __forceinline__ void xfft_dit(float2 z[16], const float2 Wt[5], int lane){
    #pragma unroll
    for (int s = 0; s < 6; ++s){
        const int d = 1 << s;
        const bool up = (lane & d) != 0;
        const float sg = up ? -1.0f : 1.0f;
        float2 w;
        if (d > 1) w = up ? Wt[s - 1] : make_float2(1.0f, 0.0f);
        #pragma unroll
        for (int r = 0; r < 16; ++r){
            float2 zz = (d > 1) ? cmul(z[r], w) : z[r];
            float2 o  = shfl_xor2(zz, d);
            z[r] = make_float2(fmaf(sg, zz.x, o.x), fmaf(sg, zz.y, o.y));
        }
    }
}

// tab layout: [0 .. 6*TLEN)  = exp(i*W[l][t])  (weight phasors)
//             [6*TLEN .. 7*TLEN) = wmid[lane][r] = exp(-2pi*i*bitrev6(lane)*r/1024)
__global__ void tab_kernel(const float* __restrict__ W, float2* __restrict__ tab){
    int i = blockIdx.x * 256 + threadIdx.x;
    if (i < 6 * TLEN){
        float sv, cv; sincosf(W[i], &sv, &cv);
        tab[i] = make_float2(cv, sv);
    } else if (i < 7 * TLEN){
        int j = i - 6 * TLEN;
        int l = j >> 4, r = j & 15;
        int cb = bitrev6(l);
        float sv, cv;
        sincosf(-6.28318530717958647692f * (float)(cb * r) / 1024.0f, &sv, &cv);
        tab[i] = make_float2(cv, sv);
    }
}

template<bool TAB>
__global__ __launch_bounds__(256, 4)
void phasor_kernel(const float* __restrict__ X,
                   const float* __restrict__ W,
                   const float2* __restrict__ tab,
                   float* __restrict__ out)
{
    const int lane = threadIdx.x & 63;
    const int row  = blockIdx.x * 4 + (threadIdx.x >> 6);
    const int c = bitrev6(lane);

    // shared stage twiddles: Wt[k] = exp(-i*pi*(lane mod h)/h), h = 2<<k
    float2 Wt[5];
    #pragma unroll
    for (int k = 0; k < 5; ++k){
        const int h = 2 << k;
        float sv, cv;
        sincosf(-3.14159265358979323846f * (float)(lane & (h - 1)) / (float)h, &sv, &cv);
        Wt[k] = make_float2(cv, sv);
    }
    const float theta = -6.28318530717958647692f * (float)c / 1024.0f;

    // load + encode: z = (sqrt(1-x^2), x), layout t = 16*lane + r
    float2 z[16];
    {
        const float4* px = (const float4*)(X + (size_t)row * TLEN + lane * 16);
        #pragma unroll
        for (int i = 0; i < 4; ++i){
            float4 v = px[i];
            float xs[4] = {v.x, v.y, v.z, v.w};
            #pragma unroll
            for (int j = 0; j < 4; ++j){
                float x = fminf(fmaxf(xs[j], -0.999f), 0.999f);
                z[4*i + j] = make_float2(sqrtf(fmaf(-x, x, 1.0f)), x);
            }
        }
    }

    // NOTE: all 1/sqrt(2) and 1/sqrt(1024) scales dropped — positive real scale
    // never changes angle(Z0).

    auto midtw = [&](){
        if constexpr (TAB){
            const float4* p = (const float4*)(tab + 6 * TLEN + lane * 16);
            #pragma unroll
            for (int i = 0; i < 8; ++i){
                float4 v = p[i];
                z[2*i]   = cmul(z[2*i],   make_float2(v.x, v.y));
                z[2*i+1] = cmul(z[2*i+1], make_float2(v.z, v.w));
            }
        } else {
            #pragma unroll
            for (int r = 0; r < 16; ++r){
                float sv, cv; __sincosf(theta * (float)r, &sv, &cv);
                z[r] = cmul(z[r], make_float2(cv, sv));
            }
        }
    };

    auto even_layer = [&](int l){
        // shift, consecutive layout (t = 16*lane + r)
        if constexpr (TAB){
            const float4* p = (const float4*)(tab + l * TLEN + lane * 16);
            #pragma unroll
            for (int i = 0; i < 8; ++i){
                float4 v = p[i];
                z[2*i]   = cmul(z[2*i],   make_float2(v.x, v.y));
                z[2*i+1] = cmul(z[2*i+1], make_float2(v.z, v.w));
            }
        } else {
            const float4* p = (const float4*)(W + l * TLEN + lane * 16);
            #pragma unroll
            for (int i = 0; i < 4; ++i){
                float4 v = p[i];
                float ws[4] = {v.x, v.y, v.z, v.w};
                #pragma unroll
                for (int j = 0; j < 4; ++j){
                    float sv, cv; __sincosf(ws[j], &sv, &cv);
                    z[4*i + j] = cmul(z[4*i + j], make_float2(cv, sv));
                }
            }
        }
        // mix: adjacent registers
        #pragma unroll
        for (int m = 0; m < 8; ++m){
            float2 a = z[2*m], b = z[2*m+1];
            z[2*m]   = cadd(a, b);
            z[2*m+1] = csub(a, b);
        }
        xfft_dif(z, Wt, lane);
        midtw();
        fft16(z);
        // layout now strided-bitrev: reg r holds t = 64*r + c
    };

    auto odd_layer = [&](int l){
        // shift, strided layout (t = 64*r + c)
        if constexpr (TAB){
            const float2* p = tab + l * TLEN + c;
            #pragma unroll
            for (int r = 0; r < 16; ++r) z[r] = cmul(z[r], p[r << 6]);
        } else {
            const float* p = W + l * TLEN + c;
            #pragma unroll
            for (int r = 0; r < 16; ++r){
                float sv, cv; __sincosf(p[r << 6], &sv, &cv);
                z[r] = cmul(z[r], make_float2(cv, sv));
            }
        }
        // mix: partner lane^32 (t parity = lane bit5)
        const float sgm = (lane & 32) ? -1.0f : 1.0f;
        #pragma unroll
        for (int r = 0; r < 16; ++r){
            float2 o = shfl_xor2(z[r], 32);
            z[r] = make_float2(fmaf(sgm, z[r].x, o.x), fmaf(sgm, z[r].y, o.y));
        }
        fft16(z);
        midtw();
        xfft_dit(z, Wt, lane);
        // layout back to consecutive
    };

    even_layer(0); odd_layer(1);
    even_layer(2); odd_layer(3);
    even_layer(4);

    // ---- layer 5 shortcut: Z0 ∝ Σ_{even t} z_t * exp(i*w5[t]).
    // strided-bitrev layout: even t <=> even c <=> lane < 32.
    {
        if constexpr (TAB){
            const float2* p = tab + 5 * TLEN + c;
            #pragma unroll
            for (int r = 0; r < 16; ++r) z[r] = cmul(z[r], p[r << 6]);
        } else {
            const float* p = W + 5 * TLEN + c;
            #pragma unroll
            for (int r = 0; r < 16; ++r){
                float sv, cv; __sincosf(p[r << 6], &sv, &cv);
                z[r] = cmul(z[r], make_float2(cv, sv));
            }
        }
        float2 s = z[0];
        #pragma unroll
        for (int r = 1; r < 16; ++r) s = cadd(s, z[r]);
        // reduce lanes 0..31 only (masks <=16 never mix the halves; upper-half
        // garbage stays in upper half)
        #pragma unroll
        for (int m = 1; m <= 16; m <<= 1) s = cadd(s, shfl_xor2(s, m));
        if (lane == 0){
            out[row] = fmaf(s.y * rsqrtf(fmaf(s.x, s.x, s.y * s.y)), 0.5f, 0.5f);
        }
    }
}

extern "C" void kernel_launch(void* const* d_in, const int* in_sizes, int n_in,
                              void* d_out, int out_size, void* d_ws, size_t ws_size,
                              hipStream_t stream) {
    const float* X = (const float*)d_in[0];   // [4096, 1024]
    const float* W = (const float*)d_in[1];   // [6*1024]
    float* out = (float*)d_out;               // [4096]
    (void)in_sizes; (void)n_in; (void)out_size;

    const size_t need = (size_t)7 * TLEN * sizeof(float2);  // 57344 B
    if (d_ws && ws_size >= need){
        float2* tab = (float2*)d_ws;
        tab_kernel<<<(7 * TLEN + 255) / 256, 256, 0, stream>>>(W, tab);
        phasor_kernel<true><<<4096 / 4, 256, 0, stream>>>(X, W, tab, out);
    } else {
        phasor_kernel<false><<<4096 / 4, 256, 0, stream>>>(X, W, nullptr, out);
    }
}

// Round 4
// 59.584 us; speedup vs baseline: 1.7022x; 1.1401x over previous
//
#include <hip/hip_runtime.h>
#include <math.h>

#define TLEN 1024

typedef int i32x2 __attribute__((ext_vector_type(2)));

__device__ __forceinline__ float2 cadd(float2 a, float2 b){ return make_float2(a.x+b.x, a.y+b.y); }
__device__ __forceinline__ float2 csub(float2 a, float2 b){ return make_float2(a.x-b.x, a.y-b.y); }
__device__ __forceinline__ float2 cmul(float2 a, float2 b){
    return make_float2(fmaf(a.x, b.x, -(a.y*b.y)), fmaf(a.x, b.y, a.y*b.x));
}
__device__ __forceinline__ float2 cmulnegi(float2 a){ return make_float2(a.y, -a.x); } // a * (-i)
__device__ __forceinline__ int bitrev6(int l){
    return ((l & 1) << 5) | ((l & 2) << 3) | ((l & 4) << 1)
         | ((l & 8) >> 1) | ((l & 16) >> 3) | ((l & 32) >> 5);
}

// ---- cross-lane partner primitives ----
// xor1/xor2: DPP quad_perm; xor8: DPP row_ror:8; xor4/xor16: ds_swizzle;
// xor32: v_permlane32_swap (VALU) + cndmask select.
#define DPP_XOR1  0xB1   // quad_perm [1,0,3,2]
#define DPP_XOR2  0x4E   // quad_perm [2,3,0,1]
#define DPP_XOR8  0x128  // row_ror:8  ((i+8)%16 == i^8)
#define SWZ_XOR4  0x101F // bitmode: xor=4, and=0x1F
#define SWZ_XOR16 0x401F // bitmode: xor=16, and=0x1F

template<int CTRL>
__device__ __forceinline__ float2 dpp2(float2 v){
    return make_float2(
        __int_as_float(__builtin_amdgcn_mov_dpp(__float_as_int(v.x), CTRL, 0xF, 0xF, false)),
        __int_as_float(__builtin_amdgcn_mov_dpp(__float_as_int(v.y), CTRL, 0xF, 0xF, false)));
}
template<int PAT>
__device__ __forceinline__ float2 swz2(float2 v){
    return make_float2(
        __int_as_float(__builtin_amdgcn_ds_swizzle(__float_as_int(v.x), PAT)),
        __int_as_float(__builtin_amdgcn_ds_swizzle(__float_as_int(v.y), PAT)));
}
__device__ __forceinline__ float p32f(float v, bool up){
#if __has_builtin(__builtin_amdgcn_permlane32_swap)
    i32x2 r = __builtin_amdgcn_permlane32_swap(__float_as_int(v), __float_as_int(v), false, false);
    return __int_as_float(up ? r[0] : r[1]);
#else
    int a = __float_as_int(v), b = __float_as_int(v);
    asm("v_permlane32_swap_b32 %0, %1" : "+v"(a), "+v"(b));
    return __int_as_float(up ? a : b);
#endif
}
__device__ __forceinline__ float2 p32_2(float2 v, bool up){
    return make_float2(p32f(v.x, up), p32f(v.y, up));
}

// DFT-4 (radix-2x2)
__device__ __forceinline__ void dft4(float2 x0, float2 x1, float2 x2, float2 x3,
                                     float2& y0, float2& y1, float2& y2, float2& y3){
    float2 t0 = cadd(x0, x2);
    float2 t1 = csub(x0, x2);
    float2 t2 = cadd(x1, x3);
    float2 t3 = csub(x1, x3);
    float2 n3 = cmulnegi(t3);
    y0 = cadd(t0, t2);
    y2 = csub(t0, t2);
    y1 = cadd(t1, n3);
    y3 = csub(t1, n3);
}

// in-lane 16-point DFT, natural in -> natural out
__device__ __forceinline__ void fft16(float2 z[16]){
    const float C1 = 0.92387953251128675613f, S1 = 0.38268343236508977173f;
    const float H  = 0.70710678118654752440f;
    const float2 W1 = make_float2( C1, -S1);
    const float2 W2 = make_float2(  H,  -H);
    const float2 W3 = make_float2( S1, -C1);
    const float2 W6 = make_float2( -H,  -H);
    const float2 W9 = make_float2(-C1,  S1);

    float2 A0[4], A1[4], A2[4], A3[4];
    #pragma unroll
    for (int b = 0; b < 4; ++b)
        dft4(z[b], z[4+b], z[8+b], z[12+b], A0[b], A1[b], A2[b], A3[b]);

    A1[1] = cmul(A1[1], W1);  A1[2] = cmul(A1[2], W2);  A1[3] = cmul(A1[3], W3);
    A2[1] = cmul(A2[1], W2);  A2[2] = cmulnegi(A2[2]);  A2[3] = cmul(A2[3], W6);
    A3[1] = cmul(A3[1], W3);  A3[2] = cmul(A3[2], W6);  A3[3] = cmul(A3[3], W9);

    dft4(A0[0], A0[1], A0[2], A0[3], z[0], z[4], z[8],  z[12]);
    dft4(A1[0], A1[1], A1[2], A1[3], z[1], z[5], z[9],  z[13]);
    dft4(A2[0], A2[1], A2[2], A2[3], z[2], z[6], z[10], z[14]);
    dft4(A3[0], A3[1], A3[2], A3[3], z[3], z[7], z[11], z[15]);
}

// one DIF stage: o = partner(z); pre = o + sg*z; z = TW ? (pre * w) : pre
template<bool TW, typename F>
__device__ __forceinline__ void dif_stage(float2 z[16], F partner, float sg, float2 w){
    #pragma unroll
    for (int r = 0; r < 16; ++r){
        float2 o = partner(z[r]);
        float2 pre = make_float2(fmaf(sg, z[r].x, o.x), fmaf(sg, z[r].y, o.y));
        z[r] = TW ? cmul(pre, w) : pre;
    }
}
// one DIT stage: zz = TW ? z*w : z; o = partner(zz); z = o + sg*zz
template<bool TW, typename F>
__device__ __forceinline__ void dit_stage(float2 z[16], F partner, float sg, float2 w){
    #pragma unroll
    for (int r = 0; r < 16; ++r){
        float2 zz = TW ? cmul(z[r], w) : z[r];
        float2 o = partner(zz);
        z[r] = make_float2(fmaf(sg, zz.x, o.x), fmaf(sg, zz.y, o.y));
    }
}

// cross-lane DIF FFT-64: natural in -> bit-reversed out
__device__ __forceinline__ void xfft_dif(float2 z[16], const float2 Wt[5], int lane){
    const float2 ONE = make_float2(1.0f, 0.0f);
    {   const bool up = (lane & 32) != 0; const float sg = up ? -1.0f : 1.0f;
        dif_stage<true>(z, [&](float2 v){ return p32_2(v, up); }, sg, up ? Wt[4] : ONE); }
    {   const bool up = (lane & 16) != 0; const float sg = up ? -1.0f : 1.0f;
        dif_stage<true>(z, [](float2 v){ return swz2<SWZ_XOR16>(v); }, sg, up ? Wt[3] : ONE); }
    {   const bool up = (lane & 8) != 0;  const float sg = up ? -1.0f : 1.0f;
        dif_stage<true>(z, [](float2 v){ return dpp2<DPP_XOR8>(v); }, sg, up ? Wt[2] : ONE); }
    {   const bool up = (lane & 4) != 0;  const float sg = up ? -1.0f : 1.0f;
        dif_stage<true>(z, [](float2 v){ return swz2<SWZ_XOR4>(v); }, sg, up ? Wt[1] : ONE); }
    {   const bool up = (lane & 2) != 0;  const float sg = up ? -1.0f : 1.0f;
        dif_stage<true>(z, [](float2 v){ return dpp2<DPP_XOR2>(v); }, sg, up ? Wt[0] : ONE); }
    {   const float sg = (lane & 1) ? -1.0f : 1.0f;
        dif_stage<false>(z, [](float2 v){ return dpp2<DPP_XOR1>(v); }, sg, ONE); }
}

// cross-lane DIT FFT-64: bit-reversed in -> natural out
__device__ __forceinline__ void xfft_dit(float2 z[16], const float2 Wt[5], int lane){
    const float2 ONE = make_float2(1.0f, 0.0f);
    {   const float sg = (lane & 1) ? -1.0f : 1.0f;
        dit_stage<false>(z, [](float2 v){ return dpp2<DPP_XOR1>(v); }, sg, ONE); }
    {   const bool up = (lane & 2) != 0;  const float sg = up ? -1.0f : 1.0f;
        dit_stage<true>(z, [](float2 v){ return dpp2<DPP_XOR2>(v); }, sg, up ? Wt[0] : ONE); }
    {   const bool up = (lane & 4) != 0;  const float sg = up ? -1.0f : 1.0f;
        dit_stage<true>(z, [](float2 v){ return swz2<SWZ_XOR4>(v); }, sg, up ? Wt[1] : ONE); }
    {   const bool up = (lane & 8) != 0;  const float sg = up ? -1.0f : 1.0f;
        dit_stage<true>(z, [](float2 v){ return dpp2<DPP_XOR8>(v); }, sg, up ? Wt[2] : ONE); }
    {   const bool up = (lane & 16) != 0; const float sg = up ? -1.0f : 1.0f;
        dit_stage<true>(z, [](float2 v){ return swz2<SWZ_XOR16>(v); }, sg, up ? Wt[3] : ONE); }
    {   const bool up = (lane & 32) != 0; const float sg = up ? -1.0f : 1.0f;
        dit_stage<true>(z, [&](float2 v){ return p32_2(v, up); }, sg, up ? Wt[4] : ONE); }
}

// tab layout: [0 .. 6*TLEN)  = exp(i*W[l][t])  (weight phasors)
//             [6*TLEN .. 7*TLEN) = wmid[lane][r] = exp(-2pi*i*bitrev6(lane)*r/1024)
__global__ void tab_kernel(const float* __restrict__ W, float2* __restrict__ tab){
    int i = blockIdx.x * 256 + threadIdx.x;
    if (i < 6 * TLEN){
        float sv, cv; sincosf(W[i], &sv, &cv);
        tab[i] = make_float2(cv, sv);
    } else if (i < 7 * TLEN){
        int j = i - 6 * TLEN;
        int l = j >> 4, r = j & 15;
        int cb = bitrev6(l);
        float sv, cv;
        sincosf(-6.28318530717958647692f * (float)(cb * r) / 1024.0f, &sv, &cv);
        tab[i] = make_float2(cv, sv);
    }
}

template<bool TAB>
__global__ __launch_bounds__(256, 4)
void phasor_kernel(const float* __restrict__ X,
                   const float* __restrict__ W,
                   const float2* __restrict__ tab,
                   float* __restrict__ out)
{
    const int lane = threadIdx.x & 63;
    const int row  = blockIdx.x * 4 + (threadIdx.x >> 6);
    const int c = bitrev6(lane);

    // shared stage twiddles: Wt[k] = exp(-i*pi*(lane mod h)/h), h = 2<<k
    float2 Wt[5];
    #pragma unroll
    for (int k = 0; k < 5; ++k){
        const int h = 2 << k;
        float sv, cv;
        sincosf(-3.14159265358979323846f * (float)(lane & (h - 1)) / (float)h, &sv, &cv);
        Wt[k] = make_float2(cv, sv);
    }
    const float theta = -6.28318530717958647692f * (float)c / 1024.0f;

    // load + encode: z = (sqrt(1-x^2), x), layout t = 16*lane + r
    float2 z[16];
    {
        const float4* px = (const float4*)(X + (size_t)row * TLEN + lane * 16);
        #pragma unroll
        for (int i = 0; i < 4; ++i){
            float4 v = px[i];
            float xs[4] = {v.x, v.y, v.z, v.w};
            #pragma unroll
            for (int j = 0; j < 4; ++j){
                float x = fminf(fmaxf(xs[j], -0.999f), 0.999f);
                z[4*i + j] = make_float2(sqrtf(fmaf(-x, x, 1.0f)), x);
            }
        }
    }

    // all positive real scales (1/sqrt2, 1/sqrt1024) dropped — angle-invariant.

    auto midtw = [&](){
        if constexpr (TAB){
            const float4* p = (const float4*)(tab + 6 * TLEN + lane * 16);
            #pragma unroll
            for (int i = 0; i < 8; ++i){
                float4 v = p[i];
                z[2*i]   = cmul(z[2*i],   make_float2(v.x, v.y));
                z[2*i+1] = cmul(z[2*i+1], make_float2(v.z, v.w));
            }
        } else {
            #pragma unroll
            for (int r = 0; r < 16; ++r){
                float sv, cv; __sincosf(theta * (float)r, &sv, &cv);
                z[r] = cmul(z[r], make_float2(cv, sv));
            }
        }
    };

    auto even_layer = [&](int l){
        if constexpr (TAB){
            const float4* p = (const float4*)(tab + l * TLEN + lane * 16);
            #pragma unroll
            for (int i = 0; i < 8; ++i){
                float4 v = p[i];
                z[2*i]   = cmul(z[2*i],   make_float2(v.x, v.y));
                z[2*i+1] = cmul(z[2*i+1], make_float2(v.z, v.w));
            }
        } else {
            const float4* p = (const float4*)(W + l * TLEN + lane * 16);
            #pragma unroll
            for (int i = 0; i < 4; ++i){
                float4 v = p[i];
                float ws[4] = {v.x, v.y, v.z, v.w};
                #pragma unroll
                for (int j = 0; j < 4; ++j){
                    float sv, cv; __sincosf(ws[j], &sv, &cv);
                    z[4*i + j] = cmul(z[4*i + j], make_float2(cv, sv));
                }
            }
        }
        // mix: adjacent registers
        #pragma unroll
        for (int m = 0; m < 8; ++m){
            float2 a = z[2*m], b = z[2*m+1];
            z[2*m]   = cadd(a, b);
            z[2*m+1] = csub(a, b);
        }
        xfft_dif(z, Wt, lane);
        midtw();
        fft16(z);
        // layout now strided-bitrev: reg r holds t = 64*r + c
    };

    auto odd_layer = [&](int l){
        if constexpr (TAB){
            const float2* p = tab + l * TLEN + c;
            #pragma unroll
            for (int r = 0; r < 16; ++r) z[r] = cmul(z[r], p[r << 6]);
        } else {
            const float* p = W + l * TLEN + c;
            #pragma unroll
            for (int r = 0; r < 16; ++r){
                float sv, cv; __sincosf(p[r << 6], &sv, &cv);
                z[r] = cmul(z[r], make_float2(cv, sv));
            }
        }
        // mix: partner lane^32 (t parity = lane bit5)
        const bool upm = (lane & 32) != 0;
        const float sgm = upm ? -1.0f : 1.0f;
        #pragma unroll
        for (int r = 0; r < 16; ++r){
            float2 o = p32_2(z[r], upm);
            z[r] = make_float2(fmaf(sgm, z[r].x, o.x), fmaf(sgm, z[r].y, o.y));
        }
        fft16(z);
        midtw();
        xfft_dit(z, Wt, lane);
        // layout back to consecutive
    };

    even_layer(0); odd_layer(1);
    even_layer(2); odd_layer(3);
    even_layer(4);

    // ---- layer 5 shortcut: Z0 ∝ Σ_{even t} z_t * exp(i*w5[t]).
    // strided-bitrev layout: even t <=> lanes 0..31.
    {
        if constexpr (TAB){
            const float2* p = tab + 5 * TLEN + c;
            #pragma unroll
            for (int r = 0; r < 16; ++r) z[r] = cmul(z[r], p[r << 6]);
        } else {
            const float* p = W + 5 * TLEN + c;
            #pragma unroll
            for (int r = 0; r < 16; ++r){
                float sv, cv; __sincosf(p[r << 6], &sv, &cv);
                z[r] = cmul(z[r], make_float2(cv, sv));
            }
        }
        float2 s = z[0];
        #pragma unroll
        for (int r = 1; r < 16; ++r) s = cadd(s, z[r]);
        // reduce lanes 0..31 (none of these primitives cross the 32-lane halves)
        s = cadd(s, dpp2<DPP_XOR1>(s));
        s = cadd(s, dpp2<DPP_XOR2>(s));
        s = cadd(s, swz2<SWZ_XOR4>(s));
        s = cadd(s, dpp2<DPP_XOR8>(s));
        s = cadd(s, swz2<SWZ_XOR16>(s));
        if (lane == 0){
            out[row] = fmaf(s.y * rsqrtf(fmaf(s.x, s.x, s.y * s.y)), 0.5f, 0.5f);
        }
    }
}

extern "C" void kernel_launch(void* const* d_in, const int* in_sizes, int n_in,
                              void* d_out, int out_size, void* d_ws, size_t ws_size,
                              hipStream_t stream) {
    const float* X = (const float*)d_in[0];   // [4096, 1024]
    const float* W = (const float*)d_in[1];   // [6*1024]
    float* out = (float*)d_out;               // [4096]
    (void)in_sizes; (void)n_in; (void)out_size;

    const size_t need = (size_t)7 * TLEN * sizeof(float2);  // 57344 B
    if (d_ws && ws_size >= need){
        float2* tab = (float2*)d_ws;
        tab_kernel<<<(7 * TLEN + 255) / 256, 256, 0, stream>>>(W, tab);
        phasor_kernel<true><<<4096 / 4, 256, 0, stream>>>(X, W, tab, out);
    } else {
        phasor_kernel<false><<<4096 / 4, 256, 0, stream>>>(X, W, nullptr, out);
    }
}